// Round 3
// baseline (794.388 us; speedup 1.0000x reference)
//
#include <hip/hip_runtime.h>
#include <math.h>

#define SEARCH 7
#define PAD 3
#define S2 49
#define KNN 7
#define NCLASSES 20
#define H 64
#define W 2048
#define NPTS 131072
#define NTILES 32
#define TILEW 64
#define HALO 3
#define TCOLS (TILEW + 2*HALO)      /* 70 */
#define BUCKET_CAP 8192
#define BLOCKS_PER_TILE 16
#define MAIN_BLOCK 256

struct InvG { float v[S2]; };

__device__ __forceinline__ void insert7(unsigned long long (&s)[KNN], unsigned long long key) {
    // sorted ascending; keys unique -> strict < gives exact lex-(dist, j) order
    bool c0 = key < s[0], c1 = key < s[1], c2 = key < s[2], c3 = key < s[3],
         c4 = key < s[4], c5 = key < s[5], c6 = key < s[6];
    s[6] = c6 ? (c5 ? s[5] : key) : s[6];
    s[5] = c5 ? (c4 ? s[4] : key) : s[5];
    s[4] = c4 ? (c3 ? s[3] : key) : s[4];
    s[3] = c3 ? (c2 ? s[2] : key) : s[3];
    s[2] = c2 ? (c1 ? s[1] : key) : s[2];
    s[1] = c1 ? (c0 ? s[0] : key) : s[1];
    s[0] = c0 ? key : s[0];
}

// Bucket points by px tile. Packed entry: i | (px&63)<<17 | py<<23.
__global__ __launch_bounds__(1024) void scatter_kernel(
    const int* __restrict__ pxv, const int* __restrict__ pyv,
    int* __restrict__ gcur, unsigned* __restrict__ idxbuf)
{
    __shared__ int lcnt[NTILES];
    __shared__ int gbase[NTILES];
    int tid = threadIdx.x;
    if (tid < NTILES) lcnt[tid] = 0;
    __syncthreads();
    int i = blockIdx.x * 1024 + tid;
    int x = pxv[i];
    int y = pyv[i];
    int t = x >> 6;
    int lpos = atomicAdd(&lcnt[t], 1);
    __syncthreads();
    if (tid < NTILES) gbase[tid] = atomicAdd(&gcur[tid], lcnt[tid]);
    __syncthreads();
    unsigned packed = (unsigned)i | ((unsigned)(x & 63) << 17) | ((unsigned)y << 23);
    idxbuf[t * BUCKET_CAP + gbase[t] + lpos] = packed;
}

__global__ __launch_bounds__(MAIN_BLOCK) void knn_kernel(
    const float* __restrict__ proj_range,
    const float* __restrict__ unproj_range,
    const int* __restrict__ proj_argmax,
    const int* __restrict__ gcur,
    const unsigned* __restrict__ idxbuf,
    int* __restrict__ outv,
    InvG invg)
{
    __shared__ float tile[H][TCOLS];
    int tid = threadIdx.x;
    int t = blockIdx.x >> 4;                 // 16 blocks per tile
    int tbase = t << 6;
    int lane = tid & 63;
    int q = tid >> 6;                        // 0..3

    // stage 64 x 70 halo'd tile (circular in W), coalesced 64-wide rows
#pragma unroll
    for (int rr = 0; rr < 16; ++rr) {
        int r = rr * 4 + q;
        int gb = r * W;
        tile[r][lane] = proj_range[gb + ((tbase - HALO + lane) & (W - 1))];
        if (lane < 2 * HALO)
            tile[r][64 + lane] = proj_range[gb + ((tbase - HALO + 64 + lane) & (W - 1))];
    }
    __syncthreads();

    int count = gcur[t];
    for (int slot = (blockIdx.x & 15) * MAIN_BLOCK + tid; slot < count;
         slot += BLOCKS_PER_TILE * MAIN_BLOCK) {
        unsigned pk = idxbuf[t * BUCKET_CAP + slot];
        int i  = (int)(pk & 0x1FFFFu);
        int xl = (int)((pk >> 17) & 63u);
        int y  = (int)((pk >> 23) & 63u);
        int lx = xl + HALO;                  // 3..66
        float u = unproj_range[i];

        unsigned long long keys[KNN];
#pragma unroll
        for (int k = 0; k < KNN; ++k) keys[k] = ~0ull;

#pragma unroll
        for (int dy = -PAD; dy <= PAD; ++dy) {
            int row = y + dy;
            bool vrow = (row >= 0) && (row < H);
            int rc = min(max(row, 0), H - 1);
            const float* trow = &tile[rc][lx];
#pragma unroll
            for (int dx = -PAD; dx <= PAD; ++dx) {
                const int j = (dy + PAD) * SEARCH + (dx + PAD);
                float d;
                if (j == (S2 - 1) / 2) {
                    d = 0.0f;                // center: |u-u|*invg = 0 exactly
                } else {
                    float nb = trow[dx];
                    nb = vrow ? nb : 0.0f;
                    nb = (nb < 0.0f) ? __builtin_inff() : nb;
                    d = fabsf(nb - u) * invg.v[j];
                }
                unsigned long long key =
                    ((unsigned long long)__float_as_uint(d) << 6) | (unsigned)j;
                insert7(keys, key);
            }
        }

        // gather classes for winners (global; only 7/pt); dist > 1.0 -> no vote
        int x = tbase + xl;
        int cls[KNN];
#pragma unroll
        for (int k = 0; k < KNN; ++k) {
            unsigned long long key = keys[k];
            int j = (int)(key & 63u);
            bool sel = (key >> 6) <= 0x3f800000ull;
            int dy7 = (j * 37) >> 8;         // j/7 for j in [0,55]
            int row = y + dy7 - PAD;
            bool vrow = (unsigned)row < (unsigned)H;
            int rc = min(max(row, 0), H - 1);
            int col = x + (j - dy7 * 7 - PAD);
            col += (col < 0) ? W : 0;
            col -= (col >= W) ? W : 0;
            int c = proj_argmax[rc * W + col];
            cls[k] = (sel && vrow) ? c : 0;
        }

        // pairwise vote; score = (cnt<<5)|(31-cls) so ties -> lowest class
        int cnt[KNN];
#pragma unroll
        for (int k = 0; k < KNN; ++k) cnt[k] = 1;
#pragma unroll
        for (int a = 0; a < KNN; ++a)
#pragma unroll
            for (int b = a + 1; b < KNN; ++b) {
                bool eq = (cls[a] == cls[b]);
                cnt[a] += eq ? 1 : 0;
                cnt[b] += eq ? 1 : 0;
            }
        int best = 0;
#pragma unroll
        for (int k = 0; k < KNN; ++k) {
            bool valid = (unsigned)(cls[k] - 1) < (unsigned)(NCLASSES - 1);
            int score = valid ? ((cnt[k] << 5) | (31 - cls[k])) : 0;
            best = max(best, score);
        }
        outv[i] = (best == 0) ? 1 : (31 - (best & 31));
    }
}

extern "C" void kernel_launch(void* const* d_in, const int* in_sizes, int n_in,
                              void* d_out, int out_size, void* d_ws, size_t ws_size,
                              hipStream_t stream) {
    const float* proj_range   = (const float*)d_in[0];
    const float* unproj_range = (const float*)d_in[1];
    const int*   proj_argmax  = (const int*)d_in[2];
    const int*   px           = (const int*)d_in[3];
    const int*   py           = (const int*)d_in[4];
    int* out = (int*)d_out;

    int*      gcur   = (int*)d_ws;
    unsigned* idxbuf = (unsigned*)((char*)d_ws + 1024);

    // Emulate numpy float32 pipeline for the inverse-gaussian table.
    InvG invg;
    float g[S2];
    for (int yy = 0; yy < SEARCH; ++yy) {
        for (int xx = 0; xx < SEARCH; ++xx) {
            float fdx = (float)xx - 3.0f;
            float fdy = (float)yy - 3.0f;
            float s   = fdx * fdx + fdy * fdy;
            float arg = -s / 2.0f;
            float e   = (float)exp((double)arg);
            float gg  = e / 6.2831855f;
            g[yy * SEARCH + xx] = gg;
        }
    }
    float r[8];
    for (int tt = 0; tt < 8; ++tt) r[tt] = g[tt];
    int ii;
    for (ii = 8; ii + 8 <= 48; ii += 8)
        for (int tt = 0; tt < 8; ++tt) r[tt] += g[ii + tt];
    float ssum = ((r[0] + r[1]) + (r[2] + r[3])) + ((r[4] + r[5]) + (r[6] + r[7]));
    for (; ii < S2; ++ii) ssum += g[ii];
    for (int tt = 0; tt < S2; ++tt) invg.v[tt] = 1.0f - (g[tt] / ssum);

    hipMemsetAsync(d_ws, 0, NTILES * sizeof(int), stream);
    scatter_kernel<<<NPTS / 1024, 1024, 0, stream>>>(px, py, gcur, idxbuf);
    knn_kernel<<<NTILES * BLOCKS_PER_TILE, MAIN_BLOCK, 0, stream>>>(
        proj_range, unproj_range, proj_argmax, gcur, idxbuf, out, invg);
}

// Round 4
// 37.331 us; speedup vs baseline: 21.2799x; 21.2799x over previous
//
#include <hip/hip_runtime.h>
#include <math.h>

#define SEARCH 7
#define PAD 3
#define S2 49
#define KNN 7
#define NCLASSES 20
#define H 64
#define W 2048
#define NPTS 131072
#define NTILES 32
#define TILEW 64
#define TROWS 70                 /* rows -3..66 (zero-padded) */
#define TCOLS 70                 /* cols -3..66 (circular)    */
#define BUCKET_CAP 8192
#define BLOCKS_PER_TILE 16
#define MAIN_BLOCK 256

struct InvG { float v[S2]; };

// Bucket points by px tile. Packed entry: i | (px&63)<<17 | py<<23.
__global__ __launch_bounds__(1024) void scatter_kernel(
    const int* __restrict__ pxv, const int* __restrict__ pyv,
    int* __restrict__ gcur, unsigned* __restrict__ idxbuf)
{
    __shared__ int lcnt[NTILES];
    __shared__ int gbase[NTILES];
    int tid = threadIdx.x;
    if (tid < NTILES) lcnt[tid] = 0;
    __syncthreads();
    int i = blockIdx.x * 1024 + tid;
    int x = pxv[i];
    int y = pyv[i];
    int t = x >> 6;
    int lpos = atomicAdd(&lcnt[t], 1);
    __syncthreads();
    if (tid < NTILES) gbase[tid] = atomicAdd(&gcur[tid], lcnt[tid]);
    __syncthreads();
    unsigned packed = (unsigned)i | ((unsigned)(x & 63) << 17) | ((unsigned)y << 23);
    idxbuf[t * BUCKET_CAP + gbase[t] + lpos] = packed;
}

// sorted-ascending insert into named u64 registers s0..s6 (keys unique)
#define INS(KEY) do {                                                   \
    unsigned long long _k = (KEY);                                      \
    bool c0 = _k < s0, c1 = _k < s1, c2 = _k < s2, c3 = _k < s3,        \
         c4 = _k < s4, c5 = _k < s5, c6 = _k < s6;                      \
    s6 = c6 ? (c5 ? s5 : _k) : s6;                                      \
    s5 = c5 ? (c4 ? s4 : _k) : s5;                                      \
    s4 = c4 ? (c3 ? s3 : _k) : s4;                                      \
    s3 = c3 ? (c2 ? s2 : _k) : s3;                                      \
    s2 = c2 ? (c1 ? s1 : _k) : s2;                                      \
    s1 = c1 ? (c0 ? s0 : _k) : s1;                                      \
    s0 = c0 ? _k : s0;                                                  \
} while (0)

__global__ __launch_bounds__(MAIN_BLOCK) void knn_kernel(
    const float* __restrict__ proj_range,
    const float* __restrict__ unproj_range,
    const int* __restrict__ proj_argmax,
    const int* __restrict__ gcur,
    const unsigned* __restrict__ idxbuf,
    int* __restrict__ outv,
    InvG invg)
{
    __shared__ float ftile[TROWS * TCOLS];
    __shared__ int   atile[TROWS * TCOLS];
    int tid = threadIdx.x;
    int t = blockIdx.x >> 4;
    int tbase = t << 6;
    int lane = tid & 63;
    int q = tid >> 6;                        // 0..3

    // stage 70x70 padded tiles: row r holds source row r-3 (zero outside [0,64))
#pragma unroll
    for (int it = 0; it < 18; ++it) {
        int r = it * 4 + q;
        if (r < TROWS) {
            int sr = r - 3;
            bool vr = (unsigned)sr < (unsigned)H;
            int srcr = vr ? sr : 0;
            int gb = srcr * W;
            int ca = (tbase - 3 + lane) & (W - 1);
            float fv = proj_range[gb + ca];
            int   av = proj_argmax[gb + ca];
            ftile[r * TCOLS + lane] = vr ? fv : 0.0f;
            atile[r * TCOLS + lane] = vr ? av : 0;
            if (lane < TCOLS - 64) {
                int cb = (tbase - 3 + 64 + lane) & (W - 1);
                float fv2 = proj_range[gb + cb];
                int   av2 = proj_argmax[gb + cb];
                ftile[r * TCOLS + 64 + lane] = vr ? fv2 : 0.0f;
                atile[r * TCOLS + 64 + lane] = vr ? av2 : 0;
            }
        }
    }
    __syncthreads();

    int count = gcur[t];
    for (int slot = (blockIdx.x & 15) * MAIN_BLOCK + tid; slot < count;
         slot += BLOCKS_PER_TILE * MAIN_BLOCK) {
        unsigned pk = idxbuf[t * BUCKET_CAP + slot];
        int i  = (int)(pk & 0x1FFFFu);
        int xl = (int)((pk >> 17) & 63u);
        int y  = (int)((pk >> 23) & 63u);
        float u = unproj_range[i];

        unsigned long long s0 = ~0ull, s1 = ~0ull, s2 = ~0ull, s3 = ~0ull,
                           s4 = ~0ull, s5 = ~0ull, s6 = ~0ull;

        INS(24ull);   // center candidate: dist exactly 0, j=24

#pragma unroll
        for (int dy = -PAD; dy <= PAD; ++dy) {
            int base = (y + dy + 3) * TCOLS + xl + 3;    // row always in-tile
#pragma unroll
            for (int dx = -PAD; dx <= PAD; ++dx) {
                const int j = (dy + PAD) * SEARCH + (dx + PAD);
                if (j == (S2 - 1) / 2) continue;          // center handled above
                float nb = ftile[base + dx];
                nb = (nb < 0.0f) ? __builtin_inff() : nb;
                float d = fabsf(nb - u) * invg.v[j];
                INS(((unsigned long long)__float_as_uint(d) << 6) | (unsigned)j);
            }
        }

        // winner classes from padded atile (pad rows hold class 0)
        int c0, c1, c2, c3, c4, c5, c6;
#define CLSK(K, CK) do {                                                 \
        unsigned long long key = s##K;                                   \
        int j = (int)(key & 63u);                                        \
        bool sel = (key >> 6) <= 0x3f800000ull;                          \
        int dy7 = (j * 37) >> 8;                                         \
        int cc = atile[(y + dy7) * TCOLS + xl + (j - dy7 * 7)];          \
        CK = sel ? cc : 0;                                               \
    } while (0)
        CLSK(0, c0); CLSK(1, c1); CLSK(2, c2); CLSK(3, c3);
        CLSK(4, c4); CLSK(5, c5); CLSK(6, c6);
#undef CLSK

        int n0 = 1, n1 = 1, n2 = 1, n3 = 1, n4 = 1, n5 = 1, n6 = 1;
#define PAIR(A, B) do { bool e = (c##A == c##B); n##A += e ? 1 : 0; n##B += e ? 1 : 0; } while (0)
        PAIR(0,1); PAIR(0,2); PAIR(0,3); PAIR(0,4); PAIR(0,5); PAIR(0,6);
        PAIR(1,2); PAIR(1,3); PAIR(1,4); PAIR(1,5); PAIR(1,6);
        PAIR(2,3); PAIR(2,4); PAIR(2,5); PAIR(2,6);
        PAIR(3,4); PAIR(3,5); PAIR(3,6);
        PAIR(4,5); PAIR(4,6);
        PAIR(5,6);
#undef PAIR

        int best = 0;
#define SCORE(K) do {                                                    \
        bool valid = (unsigned)(c##K - 1) < (unsigned)(NCLASSES - 1);    \
        int sc = valid ? ((n##K << 5) | (31 - c##K)) : 0;                \
        best = max(best, sc);                                            \
    } while (0)
        SCORE(0); SCORE(1); SCORE(2); SCORE(3); SCORE(4); SCORE(5); SCORE(6);
#undef SCORE
        outv[i] = (best == 0) ? 1 : (31 - (best & 31));
    }
}

extern "C" void kernel_launch(void* const* d_in, const int* in_sizes, int n_in,
                              void* d_out, int out_size, void* d_ws, size_t ws_size,
                              hipStream_t stream) {
    const float* proj_range   = (const float*)d_in[0];
    const float* unproj_range = (const float*)d_in[1];
    const int*   proj_argmax  = (const int*)d_in[2];
    const int*   px           = (const int*)d_in[3];
    const int*   py           = (const int*)d_in[4];
    int* out = (int*)d_out;

    int*      gcur   = (int*)d_ws;
    unsigned* idxbuf = (unsigned*)((char*)d_ws + 1024);

    // Emulate numpy float32 pipeline for the inverse-gaussian table.
    InvG invg;
    float g[S2];
    for (int yy = 0; yy < SEARCH; ++yy) {
        for (int xx = 0; xx < SEARCH; ++xx) {
            float fdx = (float)xx - 3.0f;
            float fdy = (float)yy - 3.0f;
            float s   = fdx * fdx + fdy * fdy;
            float arg = -s / 2.0f;
            float e   = (float)exp((double)arg);
            float gg  = e / 6.2831855f;
            g[yy * SEARCH + xx] = gg;
        }
    }
    float r[8];
    for (int tt = 0; tt < 8; ++tt) r[tt] = g[tt];
    int ii;
    for (ii = 8; ii + 8 <= 48; ii += 8)
        for (int tt = 0; tt < 8; ++tt) r[tt] += g[ii + tt];
    float ssum = ((r[0] + r[1]) + (r[2] + r[3])) + ((r[4] + r[5]) + (r[6] + r[7]));
    for (; ii < S2; ++ii) ssum += g[ii];
    for (int tt = 0; tt < S2; ++tt) invg.v[tt] = 1.0f - (g[tt] / ssum);

    hipMemsetAsync(d_ws, 0, NTILES * sizeof(int), stream);
    scatter_kernel<<<NPTS / 1024, 1024, 0, stream>>>(px, py, gcur, idxbuf);
    knn_kernel<<<NTILES * BLOCKS_PER_TILE, MAIN_BLOCK, 0, stream>>>(
        proj_range, unproj_range, proj_argmax, gcur, idxbuf, out, invg);
}